// Round 1
// baseline (2992.638 us; speedup 1.0000x reference)
//
#include <hip/hip_runtime.h>
#include <math.h>

#define N_NODES 100000
#define NE      3200000
#define H       32
#define DAMPING 0.1f
#define LN_EPS  1e-5f

// ---------------------------------------------------------------------------
// Kernel 1: LayerNorm + two HxH GEMVs per row.
// block = 256 threads = 8 rows x 32 lanes (one lane per feature)
// ---------------------------------------------------------------------------
__global__ __launch_bounds__(256) void ln_xw_kernel(
    const float* __restrict__ h,
    const float* __restrict__ gamma,
    const float* __restrict__ beta,
    const float* __restrict__ Wp,
    const float* __restrict__ Wn,
    float* __restrict__ xwp_out,
    float* __restrict__ xwn_out)
{
    __shared__ float sWp[H * H];
    __shared__ float sWn[H * H];
    __shared__ float sHn[8][H];

    int tid = threadIdx.x;
    for (int i = tid; i < H * H; i += 256) { sWp[i] = Wp[i]; sWn[i] = Wn[i]; }

    int lane = tid & 31;
    int r    = tid >> 5;
    int row  = blockIdx.x * 8 + r;

    float x = h[row * H + lane];
    // mean over 32 features (xor-shuffle stays within each 32-lane group)
    float s = x;
    #pragma unroll
    for (int m = 16; m >= 1; m >>= 1) s += __shfl_xor(s, m);
    float mu = s * (1.0f / 32.0f);
    float d  = x - mu;
    float v  = d * d;
    #pragma unroll
    for (int m = 16; m >= 1; m >>= 1) v += __shfl_xor(v, m);
    float rstd = rsqrtf(v * (1.0f / 32.0f) + LN_EPS);
    float hn   = d * rstd * gamma[lane] + beta[lane];

    sHn[r][lane] = hn;
    __syncthreads();

    float accp = 0.f, accn = 0.f;
    #pragma unroll
    for (int k = 0; k < H; k++) {
        float hk = sHn[r][k];
        accp += hk * sWp[k * H + lane];
        accn += hk * sWn[k * H + lane];
    }
    xwp_out[row * H + lane] = accp;
    xwn_out[row * H + lane] = accn;
}

// ---------------------------------------------------------------------------
// Kernel 2: degree histograms (incoming edge count) for both graphs.
// ---------------------------------------------------------------------------
__global__ __launch_bounds__(256) void degree_kernel(
    const int* __restrict__ dst_pos,
    const int* __restrict__ dst_neg,
    int* __restrict__ degp,
    int* __restrict__ degn)
{
    int gid = blockIdx.x * 256 + threadIdx.x;
    if (gid < NE) {
        atomicAdd(&degp[dst_pos[gid]], 1);
    } else {
        atomicAdd(&degn[dst_neg[gid - NE]], 1);
    }
}

// ---------------------------------------------------------------------------
// Kernel 3: inv_sqrt(deg + 1)   (+1 = self loop; deg >= 1 always)
// ---------------------------------------------------------------------------
__global__ __launch_bounds__(256) void inv_kernel(
    const int* __restrict__ degp,
    const int* __restrict__ degn,
    float* __restrict__ invp,
    float* __restrict__ invn)
{
    int i = blockIdx.x * 256 + threadIdx.x;
    if (i < N_NODES) {
        invp[i] = rsqrtf((float)degp[i] + 1.0f);
        invn[i] = rsqrtf((float)degn[i] + 1.0f);
    }
}

// ---------------------------------------------------------------------------
// Kernel 4: edge aggregation, both graphs. 8 threads per edge, float4 gather,
// 4 fp32 hardware atomics per thread. 2*E*8 = 51.2M threads.
// ---------------------------------------------------------------------------
__global__ __launch_bounds__(256) void edge_agg_kernel(
    const int* __restrict__ ep,     // edge_index_pos: [0..E) src, [E..2E) dst
    const int* __restrict__ en,
    const float* __restrict__ invp,
    const float* __restrict__ invn,
    const float* __restrict__ xwp,
    const float* __restrict__ xwn,
    float* __restrict__ aggp,
    float* __restrict__ aggn)
{
    int gid  = blockIdx.x * 256 + threadIdx.x;
    int part = gid & 7;
    int e    = gid >> 3;            // 0 .. 2E

    const int* ei;
    const float* inv;
    const float* xw;
    float* agg;
    if (e < NE) { ei = ep; inv = invp; xw = xwp; agg = aggp; }
    else        { e -= NE; ei = en; inv = invn; xw = xwn; agg = aggn; }

    int src = ei[e];
    int dst = ei[NE + e];
    float coef = inv[src] * inv[dst];

    const float4* xr = (const float4*)(xw + src * H);
    float4 v = xr[part];

    float* ad = agg + dst * H + part * 4;
    unsafeAtomicAdd(ad + 0, v.x * coef);
    unsafeAtomicAdd(ad + 1, v.y * coef);
    unsafeAtomicAdd(ad + 2, v.z * coef);
    unsafeAtomicAdd(ad + 3, v.w * coef);
}

// ---------------------------------------------------------------------------
// Kernel 5: add self-loop + bias, psi projection (64x32), tanh, damping, clip.
// Recomputes LayerNorm for the damping term (cheaper than storing hn).
// ---------------------------------------------------------------------------
__global__ __launch_bounds__(256) void final_kernel(
    const float* __restrict__ h,
    const float* __restrict__ gamma,
    const float* __restrict__ beta,
    const float* __restrict__ xwp,
    const float* __restrict__ xwn,
    const float* __restrict__ aggp,
    const float* __restrict__ aggn,
    const float* __restrict__ invp,
    const float* __restrict__ invn,
    const float* __restrict__ bp,
    const float* __restrict__ bn,
    const float* __restrict__ Wpsi,   // (2H, H) row-major
    float* __restrict__ out)
{
    __shared__ float sW[2 * H * H];
    __shared__ float sP[8][H];
    __shared__ float sM[8][H];

    int tid = threadIdx.x;
    for (int i = tid; i < 2 * H * H; i += 256) sW[i] = Wpsi[i];

    int lane = tid & 31;
    int r    = tid >> 5;
    int row  = blockIdx.x * 8 + r;

    // recompute layernorm for damping term
    float x = h[row * H + lane];
    float s = x;
    #pragma unroll
    for (int m = 16; m >= 1; m >>= 1) s += __shfl_xor(s, m);
    float mu = s * (1.0f / 32.0f);
    float d  = x - mu;
    float v  = d * d;
    #pragma unroll
    for (int m = 16; m >= 1; m >>= 1) v += __shfl_xor(v, m);
    float rstd = rsqrtf(v * (1.0f / 32.0f) + LN_EPS);
    float hn   = d * rstd * gamma[lane] + beta[lane];

    float ip = invp[row];
    float im = invn[row];
    float hp = aggp[row * H + lane] + xwp[row * H + lane] * ip * ip + bp[lane];
    float hm = aggn[row * H + lane] + xwn[row * H + lane] * im * im + bn[lane];

    sP[r][lane] = hp;
    sM[r][lane] = hm;
    __syncthreads();

    float acc = 0.f;
    #pragma unroll
    for (int k = 0; k < H; k++) {
        acc += sP[r][k] * sW[k * H + lane];
        acc += sM[r][k] * sW[(H + k) * H + lane];
    }

    float delta = tanhf(acc) - DAMPING * hn;
    delta = fminf(fmaxf(delta, -50.f), 50.f);
    out[row * H + lane] = delta;
}

// ---------------------------------------------------------------------------
extern "C" void kernel_launch(void* const* d_in, const int* in_sizes, int n_in,
                              void* d_out, int out_size, void* d_ws, size_t ws_size,
                              hipStream_t stream)
{
    // inputs per setup_inputs() order
    const float* h      = (const float*)d_in[1];
    const int*   ep     = (const int*)  d_in[2];   // (2, E)
    const int*   en     = (const int*)  d_in[3];
    const float* gamma  = (const float*)d_in[4];
    const float* beta   = (const float*)d_in[5];
    const float* Wp     = (const float*)d_in[6];
    const float* bp     = (const float*)d_in[7];
    const float* Wn     = (const float*)d_in[8];
    const float* bn     = (const float*)d_in[9];
    const float* Wpsi   = (const float*)d_in[10];
    float* out = (float*)d_out;

    // workspace layout (floats)
    const size_t NH = (size_t)N_NODES * H;          // 3.2M elements
    float* xwp  = (float*)d_ws;
    float* xwn  = xwp + NH;
    float* aggp = xwn + NH;
    float* aggn = aggp + NH;
    float* invp = aggn + NH;
    float* invn = invp + N_NODES;
    int*   degp = (int*)(invn + N_NODES);
    int*   degn = degp + N_NODES;

    // zero accumulators and degree histograms
    hipMemsetAsync(aggp, 0, 2 * NH * sizeof(float), stream);          // aggp+aggn
    hipMemsetAsync(degp, 0, 2 * N_NODES * sizeof(int), stream);       // degp+degn

    ln_xw_kernel<<<N_NODES / 8, 256, 0, stream>>>(h, gamma, beta, Wp, Wn, xwp, xwn);

    degree_kernel<<<2 * NE / 256, 256, 0, stream>>>(ep + NE, en + NE, degp, degn);

    inv_kernel<<<(N_NODES + 255) / 256, 256, 0, stream>>>(degp, degn, invp, invn);

    edge_agg_kernel<<<2 * NE * 8 / 256, 256, 0, stream>>>(
        ep, en, invp, invn, xwp, xwn, aggp, aggn);

    final_kernel<<<N_NODES / 8, 256, 0, stream>>>(
        h, gamma, beta, xwp, xwn, aggp, aggn, invp, invn, bp, bn, Wpsi, out);
}

// Round 2
// 1467.842 us; speedup vs baseline: 2.0388x; 2.0388x over previous
//
#include <hip/hip_runtime.h>
#include <math.h>

#define N_NODES 100000
#define NE      3200000
#define H       32
#define NH      (N_NODES * H)
#define DAMPING 0.1f
#define LN_EPS  1e-5f
#define SCAN_M  (2 * N_NODES)
#define SCAN_T  1024
#define SCAN_CHUNK 196   // 1024*196 = 200704 >= 200000

// ---------------------------------------------------------------------------
// Kernel 1: degree histograms (incoming edge count) for both graphs.
// deg is [2N]: pos rows [0,N), neg rows [N,2N)
// ---------------------------------------------------------------------------
__global__ __launch_bounds__(256) void degree_kernel(
    const int* __restrict__ dst_pos,
    const int* __restrict__ dst_neg,
    int* __restrict__ deg)
{
    int gid = blockIdx.x * 256 + threadIdx.x;
    if (gid < NE) {
        atomicAdd(&deg[dst_pos[gid]], 1);
    } else {
        atomicAdd(&deg[N_NODES + dst_neg[gid - NE]], 1);
    }
}

// ---------------------------------------------------------------------------
// Kernel 2: inv_sqrt(deg + 1)  (+1 = self loop)
// ---------------------------------------------------------------------------
__global__ __launch_bounds__(256) void inv_kernel(
    const int* __restrict__ deg,
    float* __restrict__ inv)
{
    int i = blockIdx.x * 256 + threadIdx.x;
    if (i < SCAN_M) inv[i] = rsqrtf((float)deg[i] + 1.0f);
}

// ---------------------------------------------------------------------------
// Kernel 3: exclusive scan of deg[0..2N) -> ex[0..2N). Single 1024-thread
// block; each thread serially handles a 196-element chunk (1.6 MB traffic).
// ---------------------------------------------------------------------------
__global__ __launch_bounds__(SCAN_T) void scan_kernel(
    const int* __restrict__ deg,
    int* __restrict__ ex)
{
    __shared__ int sdata[SCAN_T];
    int t = threadIdx.x;
    int lo = t * SCAN_CHUNK;
    int hi = min(SCAN_M, lo + SCAN_CHUNK);

    int ssum = 0;
    for (int i = lo; i < hi; i++) ssum += deg[i];
    sdata[t] = ssum;
    __syncthreads();

    // Hillis-Steele inclusive scan over 1024 partials
    for (int off = 1; off < SCAN_T; off <<= 1) {
        int v = (t >= off) ? sdata[t - off] : 0;
        __syncthreads();
        sdata[t] += v;
        __syncthreads();
    }

    int run = (t == 0) ? 0 : sdata[t - 1];
    for (int i = lo; i < hi; i++) {
        ex[i] = run;
        run += deg[i];
    }
}

// ---------------------------------------------------------------------------
// Kernel 4: LayerNorm + two HxH GEMVs per row, outputs pre-scaled by inv[row]
// so per-edge coefficient work vanishes downstream.
// xws[0..NH) = (LN(h) @ Wp) * invp[row];  xws[NH..2NH) = (LN(h) @ Wn) * invn
// ---------------------------------------------------------------------------
__global__ __launch_bounds__(256) void ln_xw_kernel(
    const float* __restrict__ h,
    const float* __restrict__ gamma,
    const float* __restrict__ beta,
    const float* __restrict__ Wp,
    const float* __restrict__ Wn,
    const float* __restrict__ inv,
    float* __restrict__ xws)
{
    __shared__ float sWp[H * H];
    __shared__ float sWn[H * H];
    __shared__ float sHn[8][H];

    int tid = threadIdx.x;
    for (int i = tid; i < H * H; i += 256) { sWp[i] = Wp[i]; sWn[i] = Wn[i]; }

    int lane = tid & 31;
    int r    = tid >> 5;
    int row  = blockIdx.x * 8 + r;

    float x = h[row * H + lane];
    float s = x;
    #pragma unroll
    for (int m = 16; m >= 1; m >>= 1) s += __shfl_xor(s, m);
    float mu = s * (1.0f / 32.0f);
    float d  = x - mu;
    float v  = d * d;
    #pragma unroll
    for (int m = 16; m >= 1; m >>= 1) v += __shfl_xor(v, m);
    float rstd = rsqrtf(v * (1.0f / 32.0f) + LN_EPS);
    float hn   = d * rstd * gamma[lane] + beta[lane];

    sHn[r][lane] = hn;
    __syncthreads();

    float accp = 0.f, accn = 0.f;
    #pragma unroll
    for (int k = 0; k < H; k++) {
        float hk = sHn[r][k];
        accp += hk * sWp[k * H + lane];
        accn += hk * sWn[k * H + lane];
    }
    xws[row * H + lane]      = accp * inv[row];
    xws[NH + row * H + lane] = accn * inv[N_NODES + row];
}

// ---------------------------------------------------------------------------
// Kernel 5: scatter edges into CSR slots. atomicAdd on ex doubles as cursor;
// after this kernel ex[] holds the INCLUSIVE scan (row r spans
// [r==0?0:ex[r-1], ex[r]) ).
// ---------------------------------------------------------------------------
__global__ __launch_bounds__(256) void scatter_kernel(
    const int* __restrict__ ep,
    const int* __restrict__ en,
    int* __restrict__ ex,
    int* __restrict__ slot)
{
    int gid = blockIdx.x * 256 + threadIdx.x;
    int g   = gid >= NE;
    int e   = gid - g * NE;
    const int* ei = g ? en : ep;
    int src = ei[e];
    int dst = ei[NE + e] + g * N_NODES;
    int pos = atomicAdd(&ex[dst], 1);
    slot[pos] = src;
}

// ---------------------------------------------------------------------------
// Kernel 6: fused atomic-free gather (pos+neg) + bias + psi GEMV + tanh +
// damping + clip. 8 nodes x 32 lanes per block; lane = feature.
// ---------------------------------------------------------------------------
__global__ __launch_bounds__(256) void gather_final_kernel(
    const float* __restrict__ h,
    const float* __restrict__ gamma,
    const float* __restrict__ beta,
    const float* __restrict__ xws,
    const int* __restrict__ slot,
    const float* __restrict__ inv,
    const int* __restrict__ ex,
    const float* __restrict__ bp,
    const float* __restrict__ bn,
    const float* __restrict__ Wpsi,
    float* __restrict__ out)
{
    __shared__ float sW[2 * H * H];
    __shared__ float sP[8][H];
    __shared__ float sM[8][H];

    int tid = threadIdx.x;
    for (int i = tid; i < 2 * H * H; i += 256) sW[i] = Wpsi[i];

    int lane = tid & 31;
    int r    = tid >> 5;
    int row  = blockIdx.x * 8 + r;

    // ---- pos gather (self-loop term = xws[row], already inv-scaled) ----
    float accp = xws[row * H + lane];
    {
        int start = (row == 0) ? 0 : ex[row - 1];
        int end   = ex[row];
        int j0 = start;
        for (; j0 + 32 <= end; j0 += 32) {
            int myslot = slot[j0 + lane];
            #pragma unroll
            for (int jj = 0; jj < 32; jj++) {
                int src = __shfl(myslot, jj, 32);
                accp += xws[src * H + lane];
            }
        }
        if (j0 < end) {
            int myslot = (j0 + lane < end) ? slot[j0 + lane] : 0;
            int cnt = end - j0;
            for (int jj = 0; jj < cnt; jj++) {
                int src = __shfl(myslot, jj, 32);
                accp += xws[src * H + lane];
            }
        }
    }
    float hp = inv[row] * accp + bp[lane];

    // ---- neg gather ----
    int rn = N_NODES + row;
    float accn = xws[NH + row * H + lane];
    {
        int start = ex[rn - 1];
        int end   = ex[rn];
        int j0 = start;
        for (; j0 + 32 <= end; j0 += 32) {
            int myslot = slot[j0 + lane];
            #pragma unroll
            for (int jj = 0; jj < 32; jj++) {
                int src = __shfl(myslot, jj, 32);
                accn += xws[NH + src * H + lane];
            }
        }
        if (j0 < end) {
            int myslot = (j0 + lane < end) ? slot[j0 + lane] : 0;
            int cnt = end - j0;
            for (int jj = 0; jj < cnt; jj++) {
                int src = __shfl(myslot, jj, 32);
                accn += xws[NH + src * H + lane];
            }
        }
    }
    float hm = inv[rn] * accn + bn[lane];

    // ---- recompute layernorm for damping term ----
    float x = h[row * H + lane];
    float s = x;
    #pragma unroll
    for (int m = 16; m >= 1; m >>= 1) s += __shfl_xor(s, m);
    float mu = s * (1.0f / 32.0f);
    float d  = x - mu;
    float v  = d * d;
    #pragma unroll
    for (int m = 16; m >= 1; m >>= 1) v += __shfl_xor(v, m);
    float rstd = rsqrtf(v * (1.0f / 32.0f) + LN_EPS);
    float hn   = d * rstd * gamma[lane] + beta[lane];

    // ---- psi projection ----
    sP[r][lane] = hp;
    sM[r][lane] = hm;
    __syncthreads();

    float acc = 0.f;
    #pragma unroll
    for (int k = 0; k < H; k++) {
        acc += sP[r][k] * sW[k * H + lane];
        acc += sM[r][k] * sW[(H + k) * H + lane];
    }

    float delta = tanhf(acc) - DAMPING * hn;
    delta = fminf(fmaxf(delta, -50.f), 50.f);
    out[row * H + lane] = delta;
}

// ---------------------------------------------------------------------------
extern "C" void kernel_launch(void* const* d_in, const int* in_sizes, int n_in,
                              void* d_out, int out_size, void* d_ws, size_t ws_size,
                              hipStream_t stream)
{
    const float* h      = (const float*)d_in[1];
    const int*   ep     = (const int*)  d_in[2];   // (2, E)
    const int*   en     = (const int*)  d_in[3];
    const float* gamma  = (const float*)d_in[4];
    const float* beta   = (const float*)d_in[5];
    const float* Wp     = (const float*)d_in[6];
    const float* bp     = (const float*)d_in[7];
    const float* Wn     = (const float*)d_in[8];
    const float* bn     = (const float*)d_in[9];
    const float* Wpsi   = (const float*)d_in[10];
    float* out = (float*)d_out;

    // workspace layout
    float* xws  = (float*)d_ws;               // 2*NH floats  (25.6 MB)
    int*   slot = (int*)(xws + 2 * NH);       // 2*NE ints    (25.6 MB)
    float* inv  = (float*)(slot + 2 * NE);    // 2N floats    (0.8 MB)
    int*   deg  = (int*)(inv + SCAN_M);       // 2N ints      (0.8 MB)
    int*   ex   = deg + SCAN_M;               // 2N ints      (0.8 MB)

    hipMemsetAsync(deg, 0, SCAN_M * sizeof(int), stream);

    degree_kernel<<<2 * NE / 256, 256, 0, stream>>>(ep + NE, en + NE, deg);

    inv_kernel<<<(SCAN_M + 255) / 256, 256, 0, stream>>>(deg, inv);

    scan_kernel<<<1, SCAN_T, 0, stream>>>(deg, ex);

    ln_xw_kernel<<<N_NODES / 8, 256, 0, stream>>>(h, gamma, beta, Wp, Wn, inv, xws);

    scatter_kernel<<<2 * NE / 256, 256, 0, stream>>>(ep, en, ex, slot);

    gather_final_kernel<<<N_NODES / 8, 256, 0, stream>>>(
        h, gamma, beta, xws, slot, inv, ex, bp, bn, Wpsi, out);
}

// Round 3
// 583.578 us; speedup vs baseline: 5.1281x; 2.5152x over previous
//
#include <hip/hip_runtime.h>
#include <math.h>

#define N_NODES 100000
#define NE      3200000
#define TWO_NE  (2 * NE)
#define TWO_N   (2 * N_NODES)
#define H       32
#define NH      (N_NODES * H)
#define DAMPING 0.1f
#define LN_EPS  1e-5f

#define NBUCK   782            // ceil(2N / 256) coarse dst buckets (256 rows each)
#define EPB     8192           // edges per pass-A block
#define NBLK_A  ((TWO_NE + EPB - 1) / EPB)   // 782
#define MAXB    12288          // LDS cap per bucket (mean 8192, +45 sigma)

// ---------------------------------------------------------------------------
// Kernel 1: coarse bucket histogram (bucket = dst' >> 8, dst' in [0, 2N)).
// ---------------------------------------------------------------------------
__global__ __launch_bounds__(256) void bucket_hist_kernel(
    const int* __restrict__ ep, const int* __restrict__ en,
    int* __restrict__ ghist)
{
    __shared__ int sh[NBUCK];
    for (int i = threadIdx.x; i < NBUCK; i += 256) sh[i] = 0;
    __syncthreads();
    int stride = gridDim.x * 256;
    for (int i = blockIdx.x * 256 + threadIdx.x; i < TWO_NE; i += stride) {
        int g = i >= NE;
        int e = i - g * NE;
        int d = (g ? en[NE + e] : ep[NE + e]) + g * N_NODES;
        atomicAdd(&sh[d >> 8], 1);
    }
    __syncthreads();
    for (int i = threadIdx.x; i < NBUCK; i += 256)
        if (sh[i]) atomicAdd(&ghist[i], sh[i]);
}

// ---------------------------------------------------------------------------
// Kernel 2: scan of 782 bucket counts -> exact bucket bases + init cursors.
// ---------------------------------------------------------------------------
__global__ __launch_bounds__(1024) void bucket_scan_kernel(
    const int* __restrict__ ghist, int* __restrict__ bbase, int* __restrict__ gcur)
{
    __shared__ int s[1024];
    int t = threadIdx.x;
    int v = (t < NBUCK) ? ghist[t] : 0;
    s[t] = v;
    __syncthreads();
    for (int off = 1; off < 1024; off <<= 1) {
        int u = (t >= off) ? s[t - off] : 0;
        __syncthreads();
        s[t] += u;
        __syncthreads();
    }
    int excl = s[t] - v;
    if (t < NBUCK) { bbase[t] = excl; gcur[t] = excl; }
    if (t == NBUCK - 1) bbase[NBUCK] = s[t];     // total = 2E
}

// ---------------------------------------------------------------------------
// Kernel 3 (pass A): LDS counting-sort edges by coarse bucket; one global
// atomic claim per (block,bucket); coalesced run writes.
// rec = (dst' & 255) << 18 | src'   (src' < 2^18)
// ---------------------------------------------------------------------------
__global__ __launch_bounds__(256) void bucket_scatter_kernel(
    const int* __restrict__ ep, const int* __restrict__ en,
    int* __restrict__ gcur, unsigned int* __restrict__ bucketed)
{
    __shared__ int hist[NBUCK];
    __shared__ int lexcl[NBUCK];
    __shared__ int lcur[NBUCK];
    __shared__ int claim[NBUCK];
    __shared__ int partial[256];
    __shared__ unsigned int srec[EPB];
    __shared__ unsigned short sbid[EPB];

    int t = threadIdx.x;
    for (int i = t; i < NBUCK; i += 256) { hist[i] = 0; lcur[i] = 0; }
    __syncthreads();

    int base = blockIdx.x * EPB;
    unsigned int regR[EPB / 256];
    int regB[EPB / 256];
    #pragma unroll
    for (int j = 0; j < EPB / 256; j++) {
        int i = base + j * 256 + t;
        int b = -1; unsigned int rec = 0;
        if (i < TWO_NE) {
            int g = i >= NE;
            int e = i - g * NE;
            int src = (g ? en[e] : ep[e]) + g * N_NODES;
            int dst = (g ? en[NE + e] : ep[NE + e]) + g * N_NODES;
            b = dst >> 8;
            rec = ((unsigned int)(dst & 255) << 18) | (unsigned int)src;
            atomicAdd(&hist[b], 1);
        }
        regB[j] = b; regR[j] = rec;
    }
    __syncthreads();

    // exclusive scan over hist[0..NBUCK): 4 cells/thread + Hillis over partials
    int h0[4]; int ssum = 0;
    #pragma unroll
    for (int k = 0; k < 4; k++) {
        int idx = t * 4 + k;
        h0[k] = (idx < NBUCK) ? hist[idx] : 0;
        ssum += h0[k];
    }
    partial[t] = ssum;
    __syncthreads();
    for (int off = 1; off < 256; off <<= 1) {
        int u = (t >= off) ? partial[t - off] : 0;
        __syncthreads();
        partial[t] += u;
        __syncthreads();
    }
    int run = partial[t] - ssum;
    #pragma unroll
    for (int k = 0; k < 4; k++) {
        int idx = t * 4 + k;
        if (idx < NBUCK) lexcl[idx] = run;
        run += h0[k];
    }
    __syncthreads();

    // claim contiguous global space per nonempty bucket (1 atomic each)
    for (int b = t; b < NBUCK; b += 256) {
        int c = hist[b];
        claim[b] = c ? atomicAdd(&gcur[b], c) : 0;
    }
    __syncthreads();

    // place edges sorted-by-bucket into LDS
    #pragma unroll
    for (int j = 0; j < EPB / 256; j++) {
        int b = regB[j];
        if (b >= 0) {
            int r = atomicAdd(&lcur[b], 1);
            int s = lexcl[b] + r;
            srec[s] = regR[j];
            sbid[s] = (unsigned short)b;
        }
    }
    __syncthreads();

    // coalesced-run writes: consecutive s within a bucket -> consecutive global
    int cnt = partial[255];
    for (int s = t; s < cnt; s += 256) {
        int b = sbid[s];
        bucketed[claim[b] + (s - lexcl[b])] = srec[s];
    }
}

// ---------------------------------------------------------------------------
// Kernel 4 (pass B): per bucket, build final CSR slots + degrees + inv +
// row_start. All writes confined to one block -> single-XCD L2, dense lines.
// ---------------------------------------------------------------------------
__global__ __launch_bounds__(256) void csr_build_kernel(
    const unsigned int* __restrict__ bucketed,
    const int* __restrict__ bbase,
    int* __restrict__ slot,
    int* __restrict__ row_start,
    float* __restrict__ inv)
{
    __shared__ unsigned int recs[MAXB];
    __shared__ int hist[256];
    __shared__ int scan[256];
    __shared__ int lcur[256];

    int t = threadIdx.x;
    int b = blockIdx.x;
    int base = bbase[b];
    int cnt  = bbase[b + 1] - base;

    hist[t] = 0;
    __syncthreads();
    for (int i = t; i < cnt; i += 256) {
        unsigned int r = bucketed[base + i];
        recs[i] = r;
        atomicAdd(&hist[r >> 18], 1);
    }
    __syncthreads();
    int v = hist[t];
    scan[t] = v;
    __syncthreads();
    for (int off = 1; off < 256; off <<= 1) {
        int u = (t >= off) ? scan[t - off] : 0;
        __syncthreads();
        scan[t] += u;
        __syncthreads();
    }
    int excl = scan[t] - v;
    int row = (b << 8) + t;
    if (row < TWO_N) {
        row_start[row] = base + excl;
        inv[row] = rsqrtf((float)v + 1.0f);
    }
    lcur[t] = excl;
    __syncthreads();
    for (int i = t; i < cnt; i += 256) {
        unsigned int r = recs[i];
        int rk = atomicAdd(&lcur[r >> 18], 1);
        slot[base + rk] = (int)(r & 0x3FFFFu);
    }
    if (b == 0 && t == 0) row_start[TWO_N] = TWO_NE;
}

// ---------------------------------------------------------------------------
// Kernel 5: LayerNorm + two HxH GEMVs, outputs pre-scaled by inv[row].
// xws laid out [2N][H]: rows [0,N) = pos, [N,2N) = neg (matches src').
// ---------------------------------------------------------------------------
__global__ __launch_bounds__(256) void ln_xw_kernel(
    const float* __restrict__ h,
    const float* __restrict__ gamma,
    const float* __restrict__ beta,
    const float* __restrict__ Wp,
    const float* __restrict__ Wn,
    const float* __restrict__ inv,
    float* __restrict__ xws)
{
    __shared__ float sWp[H * H];
    __shared__ float sWn[H * H];
    __shared__ float sHn[8][H];

    int tid = threadIdx.x;
    for (int i = tid; i < H * H; i += 256) { sWp[i] = Wp[i]; sWn[i] = Wn[i]; }

    int lane = tid & 31;
    int r    = tid >> 5;
    int row  = blockIdx.x * 8 + r;

    float x = h[row * H + lane];
    float s = x;
    #pragma unroll
    for (int m = 16; m >= 1; m >>= 1) s += __shfl_xor(s, m);
    float mu = s * (1.0f / 32.0f);
    float d  = x - mu;
    float v  = d * d;
    #pragma unroll
    for (int m = 16; m >= 1; m >>= 1) v += __shfl_xor(v, m);
    float rstd = rsqrtf(v * (1.0f / 32.0f) + LN_EPS);
    float hn   = d * rstd * gamma[lane] + beta[lane];

    sHn[r][lane] = hn;
    __syncthreads();

    float accp = 0.f, accn = 0.f;
    #pragma unroll
    for (int k = 0; k < H; k++) {
        float hk = sHn[r][k];
        accp += hk * sWp[k * H + lane];
        accn += hk * sWn[k * H + lane];
    }
    xws[row * H + lane]      = accp * inv[row];
    xws[NH + row * H + lane] = accn * inv[N_NODES + row];
}

// ---------------------------------------------------------------------------
// Kernel 6: atomic-free gather (pos+neg) + bias + psi GEMV + tanh + damping.
// ---------------------------------------------------------------------------
__global__ __launch_bounds__(256) void gather_final_kernel(
    const float* __restrict__ h,
    const float* __restrict__ gamma,
    const float* __restrict__ beta,
    const float* __restrict__ xws,
    const int* __restrict__ slot,
    const float* __restrict__ inv,
    const int* __restrict__ row_start,
    const float* __restrict__ bp,
    const float* __restrict__ bn,
    const float* __restrict__ Wpsi,
    float* __restrict__ out)
{
    __shared__ float sW[2 * H * H];
    __shared__ float sP[8][H];
    __shared__ float sM[8][H];

    int tid = threadIdx.x;
    for (int i = tid; i < 2 * H * H; i += 256) sW[i] = Wpsi[i];

    int lane = tid & 31;
    int r    = tid >> 5;
    int row  = blockIdx.x * 8 + r;

    // ---- pos gather (self-loop term = xws[row], already inv-scaled) ----
    float accp = xws[row * H + lane];
    {
        int start = row_start[row];
        int end   = row_start[row + 1];
        int j0 = start;
        for (; j0 + 32 <= end; j0 += 32) {
            int myslot = slot[j0 + lane];
            #pragma unroll
            for (int jj = 0; jj < 32; jj++) {
                int src = __shfl(myslot, jj, 32);
                accp += xws[src * H + lane];
            }
        }
        if (j0 < end) {
            int myslot = (j0 + lane < end) ? slot[j0 + lane] : 0;
            int cnt = end - j0;
            for (int jj = 0; jj < cnt; jj++) {
                int src = __shfl(myslot, jj, 32);
                accp += xws[src * H + lane];
            }
        }
    }
    float hp = inv[row] * accp + bp[lane];

    // ---- neg gather (slot holds src' = src + N already) ----
    int rn = N_NODES + row;
    float accn = xws[rn * H + lane];
    {
        int start = row_start[rn];
        int end   = row_start[rn + 1];
        int j0 = start;
        for (; j0 + 32 <= end; j0 += 32) {
            int myslot = slot[j0 + lane];
            #pragma unroll
            for (int jj = 0; jj < 32; jj++) {
                int src = __shfl(myslot, jj, 32);
                accn += xws[src * H + lane];
            }
        }
        if (j0 < end) {
            int myslot = (j0 + lane < end) ? slot[j0 + lane] : 0;
            int cnt = end - j0;
            for (int jj = 0; jj < cnt; jj++) {
                int src = __shfl(myslot, jj, 32);
                accn += xws[src * H + lane];
            }
        }
    }
    float hm = inv[rn] * accn + bn[lane];

    // ---- recompute layernorm for damping term ----
    float x = h[row * H + lane];
    float s = x;
    #pragma unroll
    for (int m = 16; m >= 1; m >>= 1) s += __shfl_xor(s, m);
    float mu = s * (1.0f / 32.0f);
    float d  = x - mu;
    float v  = d * d;
    #pragma unroll
    for (int m = 16; m >= 1; m >>= 1) v += __shfl_xor(v, m);
    float rstd = rsqrtf(v * (1.0f / 32.0f) + LN_EPS);
    float hn   = d * rstd * gamma[lane] + beta[lane];

    // ---- psi projection ----
    sP[r][lane] = hp;
    sM[r][lane] = hm;
    __syncthreads();

    float acc = 0.f;
    #pragma unroll
    for (int k = 0; k < H; k++) {
        acc += sP[r][k] * sW[k * H + lane];
        acc += sM[r][k] * sW[(H + k) * H + lane];
    }

    float delta = tanhf(acc) - DAMPING * hn;
    delta = fminf(fmaxf(delta, -50.f), 50.f);
    out[row * H + lane] = delta;
}

// ---------------------------------------------------------------------------
extern "C" void kernel_launch(void* const* d_in, const int* in_sizes, int n_in,
                              void* d_out, int out_size, void* d_ws, size_t ws_size,
                              hipStream_t stream)
{
    const float* h      = (const float*)d_in[1];
    const int*   ep     = (const int*)  d_in[2];   // (2, E)
    const int*   en     = (const int*)  d_in[3];
    const float* gamma  = (const float*)d_in[4];
    const float* beta   = (const float*)d_in[5];
    const float* Wp     = (const float*)d_in[6];
    const float* bp     = (const float*)d_in[7];
    const float* Wn     = (const float*)d_in[8];
    const float* bn     = (const float*)d_in[9];
    const float* Wpsi   = (const float*)d_in[10];
    float* out = (float*)d_out;

    // workspace layout (52.8 MB total; xws aliases bucketed — bucketed is
    // dead after csr_build, xws written after by ln_xw)
    unsigned int* bucketed = (unsigned int*)d_ws;         // 2E u32 (25.6 MB)
    float*        xws      = (float*)d_ws;                // 2N*H f32 (alias)
    int*   slot      = (int*)d_ws + TWO_NE;               // 2E (25.6 MB)
    int*   row_start = slot + TWO_NE;                     // 2N+1
    float* inv       = (float*)(row_start + TWO_N + 1);   // 2N
    int*   ghist     = (int*)(inv + TWO_N);               // NBUCK
    int*   bbase     = ghist + NBUCK;                     // NBUCK+1
    int*   gcur      = bbase + NBUCK + 1;                 // NBUCK

    hipMemsetAsync(ghist, 0, NBUCK * sizeof(int), stream);

    bucket_hist_kernel<<<512, 256, 0, stream>>>(ep, en, ghist);

    bucket_scan_kernel<<<1, 1024, 0, stream>>>(ghist, bbase, gcur);

    bucket_scatter_kernel<<<NBLK_A, 256, 0, stream>>>(ep, en, gcur, bucketed);

    csr_build_kernel<<<NBUCK, 256, 0, stream>>>(bucketed, bbase, slot, row_start, inv);

    ln_xw_kernel<<<N_NODES / 8, 256, 0, stream>>>(h, gamma, beta, Wp, Wn, inv, xws);

    gather_final_kernel<<<N_NODES / 8, 256, 0, stream>>>(
        h, gamma, beta, xws, slot, inv, row_start, bp, bn, Wpsi, out);
}

// Round 4
// 420.152 us; speedup vs baseline: 7.1228x; 1.3890x over previous
//
#include <hip/hip_runtime.h>
#include <hip/hip_bf16.h>
#include <math.h>

#define N_NODES 100000
#define NE      3200000
#define TWO_NE  (2 * NE)
#define TWO_N   (2 * N_NODES)
#define H       32
#define NH      (N_NODES * H)
#define DAMPING 0.1f
#define LN_EPS  1e-5f

#define NBUCK   782            // ceil(2N / 256) coarse dst buckets (256 rows each)
#define EPB     8192           // edges per pass-A block
#define NBLK_A  ((TWO_NE + EPB - 1) / EPB)   // 782
#define MAXB    12288          // LDS cap per bucket (mean 8192, +45 sigma)

// ---------------------------------------------------------------------------
// Kernel 1: coarse bucket histogram (bucket = dst' >> 8, dst' in [0, 2N)).
// ---------------------------------------------------------------------------
__global__ __launch_bounds__(256) void bucket_hist_kernel(
    const int* __restrict__ ep, const int* __restrict__ en,
    int* __restrict__ ghist)
{
    __shared__ int sh[NBUCK];
    for (int i = threadIdx.x; i < NBUCK; i += 256) sh[i] = 0;
    __syncthreads();
    int stride = gridDim.x * 256;
    for (int i = blockIdx.x * 256 + threadIdx.x; i < TWO_NE; i += stride) {
        int g = i >= NE;
        int e = i - g * NE;
        int d = (g ? en[NE + e] : ep[NE + e]) + g * N_NODES;
        atomicAdd(&sh[d >> 8], 1);
    }
    __syncthreads();
    for (int i = threadIdx.x; i < NBUCK; i += 256)
        if (sh[i]) atomicAdd(&ghist[i], sh[i]);
}

// ---------------------------------------------------------------------------
// Kernel 2: scan of 782 bucket counts -> exact bucket bases + init cursors.
// ---------------------------------------------------------------------------
__global__ __launch_bounds__(1024) void bucket_scan_kernel(
    const int* __restrict__ ghist, int* __restrict__ bbase, int* __restrict__ gcur)
{
    __shared__ int s[1024];
    int t = threadIdx.x;
    int v = (t < NBUCK) ? ghist[t] : 0;
    s[t] = v;
    __syncthreads();
    for (int off = 1; off < 1024; off <<= 1) {
        int u = (t >= off) ? s[t - off] : 0;
        __syncthreads();
        s[t] += u;
        __syncthreads();
    }
    int excl = s[t] - v;
    if (t < NBUCK) { bbase[t] = excl; gcur[t] = excl; }
    if (t == NBUCK - 1) bbase[NBUCK] = s[t];     // total = 2E
}

// ---------------------------------------------------------------------------
// Kernel 3 (pass A): LDS counting-sort edges by coarse bucket; one global
// atomic claim per (block,bucket); coalesced run writes.
// rec = (dst' & 255) << 18 | src'   (src' < 2^18)
// ---------------------------------------------------------------------------
__global__ __launch_bounds__(256) void bucket_scatter_kernel(
    const int* __restrict__ ep, const int* __restrict__ en,
    int* __restrict__ gcur, unsigned int* __restrict__ bucketed)
{
    __shared__ int hist[NBUCK];
    __shared__ int lexcl[NBUCK];
    __shared__ int lcur[NBUCK];
    __shared__ int claim[NBUCK];
    __shared__ int partial[256];
    __shared__ unsigned int srec[EPB];
    __shared__ unsigned short sbid[EPB];

    int t = threadIdx.x;
    for (int i = t; i < NBUCK; i += 256) { hist[i] = 0; lcur[i] = 0; }
    __syncthreads();

    int base = blockIdx.x * EPB;
    unsigned int regR[EPB / 256];
    int regB[EPB / 256];
    #pragma unroll
    for (int j = 0; j < EPB / 256; j++) {
        int i = base + j * 256 + t;
        int b = -1; unsigned int rec = 0;
        if (i < TWO_NE) {
            int g = i >= NE;
            int e = i - g * NE;
            int src = (g ? en[e] : ep[e]) + g * N_NODES;
            int dst = (g ? en[NE + e] : ep[NE + e]) + g * N_NODES;
            b = dst >> 8;
            rec = ((unsigned int)(dst & 255) << 18) | (unsigned int)src;
            atomicAdd(&hist[b], 1);
        }
        regB[j] = b; regR[j] = rec;
    }
    __syncthreads();

    // exclusive scan over hist[0..NBUCK): 4 cells/thread + Hillis over partials
    int h0[4]; int ssum = 0;
    #pragma unroll
    for (int k = 0; k < 4; k++) {
        int idx = t * 4 + k;
        h0[k] = (idx < NBUCK) ? hist[idx] : 0;
        ssum += h0[k];
    }
    partial[t] = ssum;
    __syncthreads();
    for (int off = 1; off < 256; off <<= 1) {
        int u = (t >= off) ? partial[t - off] : 0;
        __syncthreads();
        partial[t] += u;
        __syncthreads();
    }
    int run = partial[t] - ssum;
    #pragma unroll
    for (int k = 0; k < 4; k++) {
        int idx = t * 4 + k;
        if (idx < NBUCK) lexcl[idx] = run;
        run += h0[k];
    }
    __syncthreads();

    // claim contiguous global space per nonempty bucket (1 atomic each)
    for (int b = t; b < NBUCK; b += 256) {
        int c = hist[b];
        claim[b] = c ? atomicAdd(&gcur[b], c) : 0;
    }
    __syncthreads();

    // place edges sorted-by-bucket into LDS
    #pragma unroll
    for (int j = 0; j < EPB / 256; j++) {
        int b = regB[j];
        if (b >= 0) {
            int r = atomicAdd(&lcur[b], 1);
            int s = lexcl[b] + r;
            srec[s] = regR[j];
            sbid[s] = (unsigned short)b;
        }
    }
    __syncthreads();

    // coalesced-run writes: consecutive s within a bucket -> consecutive global
    int cnt = partial[255];
    for (int s = t; s < cnt; s += 256) {
        int b = sbid[s];
        bucketed[claim[b] + (s - lexcl[b])] = srec[s];
    }
}

// ---------------------------------------------------------------------------
// Kernel 4 (pass B): per bucket, build final CSR slots + degrees + inv +
// row_start. All writes confined to one block -> single-XCD L2, dense lines.
// ---------------------------------------------------------------------------
__global__ __launch_bounds__(256) void csr_build_kernel(
    const unsigned int* __restrict__ bucketed,
    const int* __restrict__ bbase,
    int* __restrict__ slot,
    int* __restrict__ row_start,
    float* __restrict__ inv)
{
    __shared__ unsigned int recs[MAXB];
    __shared__ int hist[256];
    __shared__ int scan[256];
    __shared__ int lcur[256];

    int t = threadIdx.x;
    int b = blockIdx.x;
    int base = bbase[b];
    int cnt  = bbase[b + 1] - base;

    hist[t] = 0;
    __syncthreads();
    for (int i = t; i < cnt; i += 256) {
        unsigned int r = bucketed[base + i];
        recs[i] = r;
        atomicAdd(&hist[r >> 18], 1);
    }
    __syncthreads();
    int v = hist[t];
    scan[t] = v;
    __syncthreads();
    for (int off = 1; off < 256; off <<= 1) {
        int u = (t >= off) ? scan[t - off] : 0;
        __syncthreads();
        scan[t] += u;
        __syncthreads();
    }
    int excl = scan[t] - v;
    int row = (b << 8) + t;
    if (row < TWO_N) {
        row_start[row] = base + excl;
        inv[row] = rsqrtf((float)v + 1.0f);
    }
    lcur[t] = excl;
    __syncthreads();
    for (int i = t; i < cnt; i += 256) {
        unsigned int r = recs[i];
        int rk = atomicAdd(&lcur[r >> 18], 1);
        slot[base + rk] = (int)(r & 0x3FFFFu);
    }
    if (b == 0 && t == 0) row_start[TWO_N] = TWO_NE;
}

// ---------------------------------------------------------------------------
// Kernel 5: LayerNorm + two HxH GEMVs, outputs pre-scaled by inv[row],
// packed to bf16 pairs: xh[row][fp] = {feat 2fp, feat 2fp+1}, row' in [0,2N).
// ---------------------------------------------------------------------------
__global__ __launch_bounds__(256) void ln_xw_kernel(
    const float* __restrict__ h,
    const float* __restrict__ gamma,
    const float* __restrict__ beta,
    const float* __restrict__ Wp,
    const float* __restrict__ Wn,
    const float* __restrict__ inv,
    __hip_bfloat162* __restrict__ xh)
{
    __shared__ float sWp[H * H];
    __shared__ float sWn[H * H];
    __shared__ float sHn[8][H];

    int tid = threadIdx.x;
    for (int i = tid; i < H * H; i += 256) { sWp[i] = Wp[i]; sWn[i] = Wn[i]; }

    int lane = tid & 31;
    int r    = tid >> 5;
    int row  = blockIdx.x * 8 + r;

    float x = h[row * H + lane];
    float s = x;
    #pragma unroll
    for (int m = 16; m >= 1; m >>= 1) s += __shfl_xor(s, m);
    float mu = s * (1.0f / 32.0f);
    float d  = x - mu;
    float v  = d * d;
    #pragma unroll
    for (int m = 16; m >= 1; m >>= 1) v += __shfl_xor(v, m);
    float rstd = rsqrtf(v * (1.0f / 32.0f) + LN_EPS);
    float hn   = d * rstd * gamma[lane] + beta[lane];

    sHn[r][lane] = hn;
    __syncthreads();

    float accp = 0.f, accn = 0.f;
    #pragma unroll
    for (int k = 0; k < H; k++) {
        float hk = sHn[r][k];
        accp += hk * sWp[k * H + lane];
        accn += hk * sWn[k * H + lane];
    }
    float vp = accp * inv[row];
    float vn = accn * inv[N_NODES + row];

    // pack feature pairs: even lane stores {self, odd-partner}
    float vp_nb = __shfl_xor(vp, 1);
    float vn_nb = __shfl_xor(vn, 1);
    if ((lane & 1) == 0) {
        __hip_bfloat162 pv, nv;
        pv.x = __float2bfloat16(vp); pv.y = __float2bfloat16(vp_nb);
        nv.x = __float2bfloat16(vn); nv.y = __float2bfloat16(vn_nb);
        int fp = lane >> 1;
        xh[row * 16 + fp]               = pv;
        xh[(N_NODES + row) * 16 + fp]   = nv;
    }
}

// ---------------------------------------------------------------------------
// Kernel 6: atomic-free gather, wave-per-row. 64 lanes = 4 edge-groups x 16
// feature-pair lanes; 4 edges per load instruction, 1 cache line per edge.
// Then bias + psi GEMV + tanh + damping + clip.
// ---------------------------------------------------------------------------
__global__ __launch_bounds__(256) void gather_final_kernel(
    const float* __restrict__ h,
    const float* __restrict__ gamma,
    const float* __restrict__ beta,
    const __hip_bfloat162* __restrict__ xh,
    const int* __restrict__ slot,
    const float* __restrict__ inv,
    const int* __restrict__ row_start,
    const float* __restrict__ bp,
    const float* __restrict__ bn,
    const float* __restrict__ Wpsi,
    float* __restrict__ out)
{
    __shared__ float sW[2 * H * H];
    __shared__ float sP[4][H];
    __shared__ float sM[4][H];

    int tid = threadIdx.x;
    for (int i = tid; i < 2 * H * H; i += 256) sW[i] = Wpsi[i];

    int wave = tid >> 6;
    int lane = tid & 63;
    int grp  = lane >> 4;        // edge group 0..3
    int fp   = lane & 15;        // feature pair 0..15
    int row  = blockIdx.x * 4 + wave;

    float a0, a1, hp0, hp1, hm0, hm1;

    // ---- pos gather ----
    a0 = 0.f; a1 = 0.f;
    {
        int start = row_start[row];
        int end   = row_start[row + 1];
        for (int j0 = start; j0 < end; j0 += 64) {
            int batch = end - j0; if (batch > 64) batch = 64;
            int myslot = (lane < batch) ? slot[j0 + lane] : 0;
            for (int jj = 0; jj < batch; jj += 4) {
                int idx = jj + grp;
                int src = __shfl(myslot, idx, 64);
                if (idx < batch) {
                    __hip_bfloat162 v = xh[src * 16 + fp];
                    a0 += __bfloat162float(v.x);
                    a1 += __bfloat162float(v.y);
                }
            }
        }
        a0 += __shfl_xor(a0, 16); a0 += __shfl_xor(a0, 32);
        a1 += __shfl_xor(a1, 16); a1 += __shfl_xor(a1, 32);
        __hip_bfloat162 sv = xh[row * 16 + fp];          // self loop
        a0 += __bfloat162float(sv.x);
        a1 += __bfloat162float(sv.y);
        float ivr = inv[row];
        hp0 = ivr * a0 + bp[2 * fp];
        hp1 = ivr * a1 + bp[2 * fp + 1];
    }

    // ---- neg gather ----
    a0 = 0.f; a1 = 0.f;
    {
        int rn    = N_NODES + row;
        int start = row_start[rn];
        int end   = row_start[rn + 1];
        for (int j0 = start; j0 < end; j0 += 64) {
            int batch = end - j0; if (batch > 64) batch = 64;
            int myslot = (lane < batch) ? slot[j0 + lane] : 0;
            for (int jj = 0; jj < batch; jj += 4) {
                int idx = jj + grp;
                int src = __shfl(myslot, idx, 64);
                if (idx < batch) {
                    __hip_bfloat162 v = xh[src * 16 + fp];
                    a0 += __bfloat162float(v.x);
                    a1 += __bfloat162float(v.y);
                }
            }
        }
        a0 += __shfl_xor(a0, 16); a0 += __shfl_xor(a0, 32);
        a1 += __shfl_xor(a1, 16); a1 += __shfl_xor(a1, 32);
        __hip_bfloat162 sv = xh[rn * 16 + fp];           // self loop
        a0 += __bfloat162float(sv.x);
        a1 += __bfloat162float(sv.y);
        float ivr = inv[rn];
        hm0 = ivr * a0 + bn[2 * fp];
        hm1 = ivr * a1 + bn[2 * fp + 1];
    }

    if (grp == 0) {
        sP[wave][2 * fp]     = hp0;
        sP[wave][2 * fp + 1] = hp1;
        sM[wave][2 * fp]     = hm0;
        sM[wave][2 * fp + 1] = hm1;
    }
    __syncthreads();

    // ---- epilogue: LN recompute + psi + tanh + damping + clip (128 thr) ----
    if (tid < 128) {
        int r     = tid >> 5;
        int lane2 = tid & 31;
        int row2  = blockIdx.x * 4 + r;

        float x = h[row2 * H + lane2];
        float s = x;
        #pragma unroll
        for (int m = 16; m >= 1; m >>= 1) s += __shfl_xor(s, m);
        float mu = s * (1.0f / 32.0f);
        float d  = x - mu;
        float v  = d * d;
        #pragma unroll
        for (int m = 16; m >= 1; m >>= 1) v += __shfl_xor(v, m);
        float rstd = rsqrtf(v * (1.0f / 32.0f) + LN_EPS);
        float hn   = d * rstd * gamma[lane2] + beta[lane2];

        float acc = 0.f;
        #pragma unroll
        for (int k = 0; k < H; k++) {
            acc += sP[r][k] * sW[k * H + lane2];
            acc += sM[r][k] * sW[(H + k) * H + lane2];
        }

        float delta = tanhf(acc) - DAMPING * hn;
        delta = fminf(fmaxf(delta, -50.f), 50.f);
        out[row2 * H + lane2] = delta;
    }
}

// ---------------------------------------------------------------------------
extern "C" void kernel_launch(void* const* d_in, const int* in_sizes, int n_in,
                              void* d_out, int out_size, void* d_ws, size_t ws_size,
                              hipStream_t stream)
{
    const float* h      = (const float*)d_in[1];
    const int*   ep     = (const int*)  d_in[2];   // (2, E)
    const int*   en     = (const int*)  d_in[3];
    const float* gamma  = (const float*)d_in[4];
    const float* beta   = (const float*)d_in[5];
    const float* Wp     = (const float*)d_in[6];
    const float* bp     = (const float*)d_in[7];
    const float* Wn     = (const float*)d_in[8];
    const float* bn     = (const float*)d_in[9];
    const float* Wpsi   = (const float*)d_in[10];
    float* out = (float*)d_out;

    // workspace layout; xh (12.8 MB bf16) aliases bucketed (25.6 MB) —
    // bucketed is dead after csr_build, xh written after by ln_xw.
    unsigned int* bucketed = (unsigned int*)d_ws;           // 2E u32 (25.6 MB)
    __hip_bfloat162* xh    = (__hip_bfloat162*)d_ws;        // 2N*16 bf16x2 (alias)
    int*   slot      = (int*)d_ws + TWO_NE;                 // 2E (25.6 MB)
    int*   row_start = slot + TWO_NE;                       // 2N+1
    float* inv       = (float*)(row_start + TWO_N + 1);     // 2N
    int*   ghist     = (int*)(inv + TWO_N);                 // NBUCK
    int*   bbase     = ghist + NBUCK;                       // NBUCK+1
    int*   gcur      = bbase + NBUCK + 1;                   // NBUCK

    hipMemsetAsync(ghist, 0, NBUCK * sizeof(int), stream);

    bucket_hist_kernel<<<512, 256, 0, stream>>>(ep, en, ghist);

    bucket_scan_kernel<<<1, 1024, 0, stream>>>(ghist, bbase, gcur);

    bucket_scatter_kernel<<<NBLK_A, 256, 0, stream>>>(ep, en, gcur, bucketed);

    csr_build_kernel<<<NBUCK, 256, 0, stream>>>(bucketed, bbase, slot, row_start, inv);

    ln_xw_kernel<<<N_NODES / 8, 256, 0, stream>>>(h, gamma, beta, Wp, Wn, inv,
                                                  (__hip_bfloat162*)xh);

    gather_final_kernel<<<N_NODES / 4, 256, 0, stream>>>(
        h, gamma, beta, xh, slot, inv, row_start, bp, bn, Wpsi, out);
}

// Round 5
// 371.801 us; speedup vs baseline: 8.0490x; 1.1300x over previous
//
#include <hip/hip_runtime.h>
#include <hip/hip_bf16.h>
#include <math.h>

#define N_NODES 100000
#define NE      3200000
#define TWO_NE  (2 * NE)
#define TWO_N   (2 * N_NODES)
#define H       32
#define NH      (N_NODES * H)
#define DAMPING 0.1f
#define LN_EPS  1e-5f

#define NBUCK   782            // ceil(2N / 256) coarse dst buckets (256 rows each)
#define EPB     8192           // edges per pass-A block
#define NBLK_A  ((TWO_NE + EPB - 1) / EPB)   // 782

// ---------------------------------------------------------------------------
// Kernel 1: coarse bucket histogram (bucket = dst' >> 8). int4 loads.
// ---------------------------------------------------------------------------
__global__ __launch_bounds__(256) void bucket_hist_kernel(
    const int* __restrict__ ep, const int* __restrict__ en,
    int* __restrict__ ghist)
{
    __shared__ int sh[NBUCK];
    for (int i = threadIdx.x; i < NBUCK; i += 256) sh[i] = 0;
    __syncthreads();
    int stride = gridDim.x * 256;
    for (int q = blockIdx.x * 256 + threadIdx.x; q < TWO_NE / 4; q += stride) {
        int i = q * 4;                      // 4-aligned; never straddles NE
        int g = i >= NE;
        int e = i - g * NE;
        const int* dsts = (g ? en : ep) + NE;
        int4 d4 = *(const int4*)(dsts + e);
        int off = g * N_NODES;
        atomicAdd(&sh[(d4.x + off) >> 8], 1);
        atomicAdd(&sh[(d4.y + off) >> 8], 1);
        atomicAdd(&sh[(d4.z + off) >> 8], 1);
        atomicAdd(&sh[(d4.w + off) >> 8], 1);
    }
    __syncthreads();
    for (int i = threadIdx.x; i < NBUCK; i += 256)
        if (sh[i]) atomicAdd(&ghist[i], sh[i]);
}

// ---------------------------------------------------------------------------
// Kernel 2: scan of 782 bucket counts -> exact bucket bases + init cursors.
// ---------------------------------------------------------------------------
__global__ __launch_bounds__(1024) void bucket_scan_kernel(
    const int* __restrict__ ghist, int* __restrict__ bbase, int* __restrict__ gcur)
{
    __shared__ int s[1024];
    int t = threadIdx.x;
    int v = (t < NBUCK) ? ghist[t] : 0;
    s[t] = v;
    __syncthreads();
    for (int off = 1; off < 1024; off <<= 1) {
        int u = (t >= off) ? s[t - off] : 0;
        __syncthreads();
        s[t] += u;
        __syncthreads();
    }
    int excl = s[t] - v;
    if (t < NBUCK) { bbase[t] = excl; gcur[t] = excl; }
    if (t == NBUCK - 1) bbase[NBUCK] = s[t];     // total = 2E
}

// ---------------------------------------------------------------------------
// Kernel 3 (pass A): LDS counting-sort edges by coarse bucket; one global
// atomic claim per (block,bucket); coalesced run writes. int4 edge loads.
// rec = (dst' & 255) << 18 | src'   (src' < 2^18)
// ---------------------------------------------------------------------------
__global__ __launch_bounds__(256) void bucket_scatter_kernel(
    const int* __restrict__ ep, const int* __restrict__ en,
    int* __restrict__ gcur, unsigned int* __restrict__ bucketed)
{
    __shared__ int hist[NBUCK];
    __shared__ int lexcl[NBUCK];
    __shared__ int lcur[NBUCK];
    __shared__ int claim[NBUCK];
    __shared__ int partial[256];
    __shared__ unsigned int srec[EPB];
    __shared__ unsigned short sbid[EPB];

    int t = threadIdx.x;
    for (int i = t; i < NBUCK; i += 256) { hist[i] = 0; lcur[i] = 0; }
    __syncthreads();

    int base = blockIdx.x * EPB;
    unsigned int regR[EPB / 256];
    short regB[EPB / 256];
    #pragma unroll
    for (int j = 0; j < EPB / 1024; j++) {
        int i = base + (j * 256 + t) * 4;   // 4-aligned group; never straddles NE
        if (i < TWO_NE) {
            int g = i >= NE;
            int e = i - g * NE;
            const int* eix = g ? en : ep;
            int4 s4 = *(const int4*)(eix + e);
            int4 d4 = *(const int4*)(eix + NE + e);
            int off = g * N_NODES;
            int ss[4] = {s4.x, s4.y, s4.z, s4.w};
            int dd[4] = {d4.x, d4.y, d4.z, d4.w};
            #pragma unroll
            for (int k = 0; k < 4; k++) {
                int src = ss[k] + off;
                int dst = dd[k] + off;
                int b = dst >> 8;
                regB[j * 4 + k] = (short)b;
                regR[j * 4 + k] = ((unsigned int)(dst & 255) << 18) | (unsigned int)src;
                atomicAdd(&hist[b], 1);
            }
        } else {
            #pragma unroll
            for (int k = 0; k < 4; k++) regB[j * 4 + k] = -1;
        }
    }
    __syncthreads();

    // exclusive scan over hist[0..NBUCK): 4 cells/thread + Hillis over partials
    int h0[4]; int ssum = 0;
    #pragma unroll
    for (int k = 0; k < 4; k++) {
        int idx = t * 4 + k;
        h0[k] = (idx < NBUCK) ? hist[idx] : 0;
        ssum += h0[k];
    }
    partial[t] = ssum;
    __syncthreads();
    for (int off = 1; off < 256; off <<= 1) {
        int u = (t >= off) ? partial[t - off] : 0;
        __syncthreads();
        partial[t] += u;
        __syncthreads();
    }
    int run = partial[t] - ssum;
    #pragma unroll
    for (int k = 0; k < 4; k++) {
        int idx = t * 4 + k;
        if (idx < NBUCK) lexcl[idx] = run;
        run += h0[k];
    }
    __syncthreads();

    // claim contiguous global space per nonempty bucket (1 atomic each)
    for (int b = t; b < NBUCK; b += 256) {
        int c = hist[b];
        claim[b] = c ? atomicAdd(&gcur[b], c) : 0;
    }
    __syncthreads();

    // place edges sorted-by-bucket into LDS
    #pragma unroll
    for (int j = 0; j < EPB / 256; j++) {
        int b = regB[j];
        if (b >= 0) {
            int r = atomicAdd(&lcur[b], 1);
            int s = lexcl[b] + r;
            srec[s] = regR[j];
            sbid[s] = (unsigned short)b;
        }
    }
    __syncthreads();

    // coalesced-run writes: consecutive s within a bucket -> consecutive global
    int cnt = partial[255];
    for (int s = t; s < cnt; s += 256) {
        int b = sbid[s];
        bucketed[claim[b] + (s - lexcl[b])] = srec[s];
    }
}

// ---------------------------------------------------------------------------
// Kernel 4 (pass B): per bucket, build final CSR slots + row_start + inv.
// No LDS staging of records (re-read from L2-hot global) -> high occupancy.
// ---------------------------------------------------------------------------
__global__ __launch_bounds__(256) void csr_build_kernel(
    const unsigned int* __restrict__ bucketed,
    const int* __restrict__ bbase,
    int* __restrict__ slot,
    int* __restrict__ row_start,
    float* __restrict__ inv)
{
    __shared__ int hist[256];
    __shared__ int scan[256];
    __shared__ int lcur[256];

    int t = threadIdx.x;
    int b = blockIdx.x;
    int base = bbase[b];
    int cnt  = bbase[b + 1] - base;

    hist[t] = 0;
    __syncthreads();
    for (int i = t; i < cnt; i += 256)
        atomicAdd(&hist[bucketed[base + i] >> 18], 1);
    __syncthreads();
    int v = hist[t];
    scan[t] = v;
    __syncthreads();
    for (int off = 1; off < 256; off <<= 1) {
        int u = (t >= off) ? scan[t - off] : 0;
        __syncthreads();
        scan[t] += u;
        __syncthreads();
    }
    int excl = scan[t] - v;
    int row = (b << 8) + t;
    if (row < TWO_N) {
        row_start[row] = base + excl;
        inv[row] = rsqrtf((float)v + 1.0f);
    }
    lcur[t] = excl;
    __syncthreads();
    for (int i = t; i < cnt; i += 256) {
        unsigned int r = bucketed[base + i];
        int rk = atomicAdd(&lcur[r >> 18], 1);
        slot[base + rk] = (int)(r & 0x3FFFFu);
    }
    if (b == 0 && t == 0) row_start[TWO_N] = TWO_NE;
}

// ---------------------------------------------------------------------------
// Kernel 5: LayerNorm + two HxH GEMVs, outputs pre-scaled by inv[row],
// packed to bf16 pairs: xh[row][fp] = {feat 2fp, feat 2fp+1}, row' in [0,2N).
// ---------------------------------------------------------------------------
__global__ __launch_bounds__(256) void ln_xw_kernel(
    const float* __restrict__ h,
    const float* __restrict__ gamma,
    const float* __restrict__ beta,
    const float* __restrict__ Wp,
    const float* __restrict__ Wn,
    const float* __restrict__ inv,
    __hip_bfloat162* __restrict__ xh)
{
    __shared__ float sWp[H * H];
    __shared__ float sWn[H * H];
    __shared__ float sHn[8][H];

    int tid = threadIdx.x;
    for (int i = tid; i < H * H; i += 256) { sWp[i] = Wp[i]; sWn[i] = Wn[i]; }

    int lane = tid & 31;
    int r    = tid >> 5;
    int row  = blockIdx.x * 8 + r;

    float x = h[row * H + lane];
    float s = x;
    #pragma unroll
    for (int m = 16; m >= 1; m >>= 1) s += __shfl_xor(s, m);
    float mu = s * (1.0f / 32.0f);
    float d  = x - mu;
    float v  = d * d;
    #pragma unroll
    for (int m = 16; m >= 1; m >>= 1) v += __shfl_xor(v, m);
    float rstd = rsqrtf(v * (1.0f / 32.0f) + LN_EPS);
    float hn   = d * rstd * gamma[lane] + beta[lane];

    sHn[r][lane] = hn;
    __syncthreads();

    float accp = 0.f, accn = 0.f;
    #pragma unroll
    for (int k = 0; k < H; k++) {
        float hk = sHn[r][k];
        accp += hk * sWp[k * H + lane];
        accn += hk * sWn[k * H + lane];
    }
    float vp = accp * inv[row];
    float vn = accn * inv[N_NODES + row];

    // pack feature pairs: even lane stores {self, odd-partner}
    float vp_nb = __shfl_xor(vp, 1);
    float vn_nb = __shfl_xor(vn, 1);
    if ((lane & 1) == 0) {
        __hip_bfloat162 pv, nv;
        pv.x = __float2bfloat16(vp); pv.y = __float2bfloat16(vp_nb);
        nv.x = __float2bfloat16(vn); nv.y = __float2bfloat16(vn_nb);
        int fp = lane >> 1;
        xh[row * 16 + fp]               = pv;
        xh[(N_NODES + row) * 16 + fp]   = nv;
    }
}

// ---------------------------------------------------------------------------
// Row-gather with 4-deep memory-level parallelism. Wave = 4 groups x 16
// feature-pair lanes; each group handles 4 edges per chunk with all 4 loads
// issued before accumulation. Slot window (64) reloaded every 4 chunks.
// ---------------------------------------------------------------------------
__device__ __forceinline__ void gather_row(
    const __hip_bfloat162* __restrict__ xh,
    const int* __restrict__ slot,
    int start, int end, int lane, int grp, int fp,
    float& a0, float& a1)
{
    int nfull = (end - start) >> 4;     // full 16-edge chunks
    int myslot = 0;
    for (int c = 0; c < nfull; c++) {
        int base_j = start + (c << 4);
        if ((c & 3) == 0) {
            int jl = base_j + lane;
            myslot = slot[jl < end ? jl : (end - 1)];
        }
        int sb = ((c & 3) << 4) + (grp << 2);
        int s0 = __shfl(myslot, sb + 0, 64);
        int s1 = __shfl(myslot, sb + 1, 64);
        int s2 = __shfl(myslot, sb + 2, 64);
        int s3 = __shfl(myslot, sb + 3, 64);
        __hip_bfloat162 v0 = xh[s0 * 16 + fp];
        __hip_bfloat162 v1 = xh[s1 * 16 + fp];
        __hip_bfloat162 v2 = xh[s2 * 16 + fp];
        __hip_bfloat162 v3 = xh[s3 * 16 + fp];
        a0 += __bfloat162float(v0.x) + __bfloat162float(v1.x)
            + __bfloat162float(v2.x) + __bfloat162float(v3.x);
        a1 += __bfloat162float(v0.y) + __bfloat162float(v1.y)
            + __bfloat162float(v2.y) + __bfloat162float(v3.y);
    }
    // tail: < 16 edges, group-strided
    int jt = start + (nfull << 4);
    if (jt < end) {
        int cnt = end - jt;
        int ms = (lane < cnt) ? slot[jt + lane] : 0;
        for (int jj = grp; jj < cnt; jj += 4) {
            int src = __shfl(ms, jj, 64);
            __hip_bfloat162 v = xh[src * 16 + fp];
            a0 += __bfloat162float(v.x);
            a1 += __bfloat162float(v.y);
        }
    }
}

// ---------------------------------------------------------------------------
// Kernel 6: atomic-free gather (wave per row, pos+neg) + bias + psi GEMV +
// tanh + damping + clip.
// ---------------------------------------------------------------------------
__global__ __launch_bounds__(256) void gather_final_kernel(
    const float* __restrict__ h,
    const float* __restrict__ gamma,
    const float* __restrict__ beta,
    const __hip_bfloat162* __restrict__ xh,
    const int* __restrict__ slot,
    const float* __restrict__ inv,
    const int* __restrict__ row_start,
    const float* __restrict__ bp,
    const float* __restrict__ bn,
    const float* __restrict__ Wpsi,
    float* __restrict__ out)
{
    __shared__ float sW[2 * H * H];
    __shared__ float sP[4][H];
    __shared__ float sM[4][H];

    int tid = threadIdx.x;
    for (int i = tid; i < 2 * H * H; i += 256) sW[i] = Wpsi[i];

    int wave = tid >> 6;
    int lane = tid & 63;
    int grp  = lane >> 4;        // edge group 0..3
    int fp   = lane & 15;        // feature pair 0..15
    int row  = blockIdx.x * 4 + wave;

    float a0, a1;

    // ---- pos gather ----
    a0 = 0.f; a1 = 0.f;
    gather_row(xh, slot, row_start[row], row_start[row + 1], lane, grp, fp, a0, a1);
    a0 += __shfl_xor(a0, 16); a0 += __shfl_xor(a0, 32);
    a1 += __shfl_xor(a1, 16); a1 += __shfl_xor(a1, 32);
    __hip_bfloat162 svp = xh[row * 16 + fp];             // self loop
    a0 += __bfloat162float(svp.x);
    a1 += __bfloat162float(svp.y);
    float ivp = inv[row];
    float hp0 = ivp * a0 + bp[2 * fp];
    float hp1 = ivp * a1 + bp[2 * fp + 1];

    // ---- neg gather (slot holds src' = src + N already) ----
    int rn = N_NODES + row;
    a0 = 0.f; a1 = 0.f;
    gather_row(xh, slot, row_start[rn], row_start[rn + 1], lane, grp, fp, a0, a1);
    a0 += __shfl_xor(a0, 16); a0 += __shfl_xor(a0, 32);
    a1 += __shfl_xor(a1, 16); a1 += __shfl_xor(a1, 32);
    __hip_bfloat162 svn = xh[rn * 16 + fp];              // self loop
    a0 += __bfloat162float(svn.x);
    a1 += __bfloat162float(svn.y);
    float ivn = inv[rn];
    float hm0 = ivn * a0 + bn[2 * fp];
    float hm1 = ivn * a1 + bn[2 * fp + 1];

    if (grp == 0) {
        sP[wave][2 * fp]     = hp0;
        sP[wave][2 * fp + 1] = hp1;
        sM[wave][2 * fp]     = hm0;
        sM[wave][2 * fp + 1] = hm1;
    }
    __syncthreads();

    // ---- epilogue: LN recompute + psi + tanh + damping + clip (128 thr) ----
    if (tid < 128) {
        int r     = tid >> 5;
        int lane2 = tid & 31;
        int row2  = blockIdx.x * 4 + r;

        float x = h[row2 * H + lane2];
        float s = x;
        #pragma unroll
        for (int m = 16; m >= 1; m >>= 1) s += __shfl_xor(s, m);
        float mu = s * (1.0f / 32.0f);
        float d  = x - mu;
        float v  = d * d;
        #pragma unroll
        for (int m = 16; m >= 1; m >>= 1) v += __shfl_xor(v, m);
        float rstd = rsqrtf(v * (1.0f / 32.0f) + LN_EPS);
        float hn   = d * rstd * gamma[lane2] + beta[lane2];

        float acc = 0.f;
        #pragma unroll
        for (int k = 0; k < H; k++) {
            acc += sP[r][k] * sW[k * H + lane2];
            acc += sM[r][k] * sW[(H + k) * H + lane2];
        }

        float delta = tanhf(acc) - DAMPING * hn;
        delta = fminf(fmaxf(delta, -50.f), 50.f);
        out[row2 * H + lane2] = delta;
    }
}

// ---------------------------------------------------------------------------
extern "C" void kernel_launch(void* const* d_in, const int* in_sizes, int n_in,
                              void* d_out, int out_size, void* d_ws, size_t ws_size,
                              hipStream_t stream)
{
    const float* h      = (const float*)d_in[1];
    const int*   ep     = (const int*)  d_in[2];   // (2, E)
    const int*   en     = (const int*)  d_in[3];
    const float* gamma  = (const float*)d_in[4];
    const float* beta   = (const float*)d_in[5];
    const float* Wp     = (const float*)d_in[6];
    const float* bp     = (const float*)d_in[7];
    const float* Wn     = (const float*)d_in[8];
    const float* bn     = (const float*)d_in[9];
    const float* Wpsi   = (const float*)d_in[10];
    float* out = (float*)d_out;

    // workspace layout; xh (12.8 MB bf16) aliases bucketed (25.6 MB) —
    // bucketed is dead after csr_build, xh written after by ln_xw.
    unsigned int* bucketed = (unsigned int*)d_ws;           // 2E u32 (25.6 MB)
    __hip_bfloat162* xh    = (__hip_bfloat162*)d_ws;        // 2N*16 bf16x2 (alias)
    int*   slot      = (int*)d_ws + TWO_NE;                 // 2E (25.6 MB)
    int*   row_start = slot + TWO_NE;                       // 2N+1
    float* inv       = (float*)(row_start + TWO_N + 1);     // 2N
    int*   ghist     = (int*)(inv + TWO_N);                 // NBUCK
    int*   bbase     = ghist + NBUCK;                       // NBUCK+1
    int*   gcur      = bbase + NBUCK + 1;                   // NBUCK

    hipMemsetAsync(ghist, 0, NBUCK * sizeof(int), stream);

    bucket_hist_kernel<<<512, 256, 0, stream>>>(ep, en, ghist);

    bucket_scan_kernel<<<1, 1024, 0, stream>>>(ghist, bbase, gcur);

    bucket_scatter_kernel<<<NBLK_A, 256, 0, stream>>>(ep, en, gcur, bucketed);

    csr_build_kernel<<<NBUCK, 256, 0, stream>>>(bucketed, bbase, slot, row_start, inv);

    ln_xw_kernel<<<N_NODES / 8, 256, 0, stream>>>(h, gamma, beta, Wp, Wn, inv,
                                                  (__hip_bfloat162*)xh);

    gather_final_kernel<<<N_NODES / 4, 256, 0, stream>>>(
        h, gamma, beta, xh, slot, inv, row_start, bp, bn, Wpsi, out);
}

// Round 6
// 316.994 us; speedup vs baseline: 9.4407x; 1.1729x over previous
//
#include <hip/hip_runtime.h>
#include <hip/hip_bf16.h>
#include <math.h>

#define N_NODES 100000
#define NE      3200000
#define TWO_NE  (2 * NE)
#define TWO_N   (2 * N_NODES)
#define H       32
#define DAMPING 0.1f
#define LN_EPS  1e-5f

#define NBUCK   782            // ceil(2N / 256) coarse dst buckets (256 rows each)
#define CAP     8960           // bucket capacity: mean 8192 + 8.5 sigma (sigma~90.5)
#define EPB     8192           // edges per pass-A block
#define NBLK_A  ((TWO_NE + EPB - 1) / EPB)   // 782

// ---------------------------------------------------------------------------
// Kernel 0: init per-bucket cursors to fixed-capacity bases (replaces the
// exact histogram + scan of R5; overflow prob ~1e-14 at +8.5 sigma).
// ---------------------------------------------------------------------------
__global__ __launch_bounds__(256) void init_gcur_kernel(int* __restrict__ gcur)
{
    int i = blockIdx.x * 256 + threadIdx.x;
    if (i < NBUCK) gcur[i] = i * CAP;
}

// ---------------------------------------------------------------------------
// Kernel 1 (pass A): LDS counting-sort edges by coarse bucket; one global
// atomic claim per (block,bucket); coalesced run writes. int4 edge loads.
// rec = (dst' & 255) << 18 | src'   (src' < 2^18)
// ---------------------------------------------------------------------------
__global__ __launch_bounds__(256) void bucket_scatter_kernel(
    const int* __restrict__ ep, const int* __restrict__ en,
    int* __restrict__ gcur, unsigned int* __restrict__ bucketed)
{
    __shared__ int hist[NBUCK];
    __shared__ int lexcl[NBUCK];
    __shared__ int lcur[NBUCK];
    __shared__ int claim[NBUCK];
    __shared__ int partial[256];
    __shared__ unsigned int srec[EPB];
    __shared__ unsigned short sbid[EPB];

    int t = threadIdx.x;
    for (int i = t; i < NBUCK; i += 256) { hist[i] = 0; lcur[i] = 0; }
    __syncthreads();

    int base = blockIdx.x * EPB;
    unsigned int regR[EPB / 256];
    short regB[EPB / 256];
    #pragma unroll
    for (int j = 0; j < EPB / 1024; j++) {
        int i = base + (j * 256 + t) * 4;   // 4-aligned group; never straddles NE
        if (i < TWO_NE) {
            int g = i >= NE;
            int e = i - g * NE;
            const int* eix = g ? en : ep;
            int4 s4 = *(const int4*)(eix + e);
            int4 d4 = *(const int4*)(eix + NE + e);
            int off = g * N_NODES;
            int ss[4] = {s4.x, s4.y, s4.z, s4.w};
            int dd[4] = {d4.x, d4.y, d4.z, d4.w};
            #pragma unroll
            for (int k = 0; k < 4; k++) {
                int src = ss[k] + off;
                int dst = dd[k] + off;
                int b = dst >> 8;
                regB[j * 4 + k] = (short)b;
                regR[j * 4 + k] = ((unsigned int)(dst & 255) << 18) | (unsigned int)src;
                atomicAdd(&hist[b], 1);
            }
        } else {
            #pragma unroll
            for (int k = 0; k < 4; k++) regB[j * 4 + k] = -1;
        }
    }
    __syncthreads();

    // exclusive scan over hist[0..NBUCK): 4 cells/thread + Hillis over partials
    int h0[4]; int ssum = 0;
    #pragma unroll
    for (int k = 0; k < 4; k++) {
        int idx = t * 4 + k;
        h0[k] = (idx < NBUCK) ? hist[idx] : 0;
        ssum += h0[k];
    }
    partial[t] = ssum;
    __syncthreads();
    for (int off = 1; off < 256; off <<= 1) {
        int u = (t >= off) ? partial[t - off] : 0;
        __syncthreads();
        partial[t] += u;
        __syncthreads();
    }
    int run = partial[t] - ssum;
    #pragma unroll
    for (int k = 0; k < 4; k++) {
        int idx = t * 4 + k;
        if (idx < NBUCK) lexcl[idx] = run;
        run += h0[k];
    }
    __syncthreads();

    // claim contiguous global space per nonempty bucket (1 atomic each)
    for (int b = t; b < NBUCK; b += 256) {
        int c = hist[b];
        claim[b] = c ? atomicAdd(&gcur[b], c) : 0;
    }
    __syncthreads();

    // place edges sorted-by-bucket into LDS
    #pragma unroll
    for (int j = 0; j < EPB / 256; j++) {
        int b = regB[j];
        if (b >= 0) {
            int r = atomicAdd(&lcur[b], 1);
            int s = lexcl[b] + r;
            srec[s] = regR[j];
            sbid[s] = (unsigned short)b;
        }
    }
    __syncthreads();

    // coalesced-run writes: consecutive s within a bucket -> consecutive global
    int cnt = partial[255];
    for (int s = t; s < cnt; s += 256) {
        int b = sbid[s];
        bucketed[claim[b] + (s - lexcl[b])] = srec[s];
    }
}

// ---------------------------------------------------------------------------
// Kernel 2 (pass B): per bucket, in-place: read bucket into LDS, build row
// bounds (int2), inv, and write back dst-sorted src' slots to the SAME array.
// ---------------------------------------------------------------------------
__global__ __launch_bounds__(256) void csr_build_kernel(
    const int* __restrict__ gcur,
    unsigned int* __restrict__ buf,     // bucketed in, slots out (in-place)
    int2* __restrict__ rs2,
    float* __restrict__ inv)
{
    __shared__ unsigned int recs[CAP];
    __shared__ int hist[256];
    __shared__ int scan[256];
    __shared__ int lcur[256];

    int t = threadIdx.x;
    int b = blockIdx.x;
    int gbase = b * CAP;
    int cnt = gcur[b] - gbase;
    if (cnt > CAP) cnt = CAP;           // paranoia (never in practice)

    hist[t] = 0;
    __syncthreads();
    for (int i = t; i < cnt; i += 256) {
        unsigned int r = buf[gbase + i];
        recs[i] = r;
        atomicAdd(&hist[r >> 18], 1);
    }
    __syncthreads();
    int v = hist[t];
    scan[t] = v;
    __syncthreads();
    for (int off = 1; off < 256; off <<= 1) {
        int u = (t >= off) ? scan[t - off] : 0;
        __syncthreads();
        scan[t] += u;
        __syncthreads();
    }
    int excl = scan[t] - v;
    int row = (b << 8) + t;
    if (row < TWO_N) {
        rs2[row] = make_int2(gbase + excl, gbase + excl + v);
        inv[row] = rsqrtf((float)v + 1.0f);
    }
    lcur[t] = excl;
    __syncthreads();
    for (int i = t; i < cnt; i += 256) {
        unsigned int r = recs[i];
        int rk = atomicAdd(&lcur[r >> 18], 1);
        buf[gbase + rk] = r & 0x3FFFFu;
    }
}

// ---------------------------------------------------------------------------
// Kernel 3: LayerNorm + two HxH GEMVs, outputs pre-scaled by inv[row],
// packed to bf16 pairs: xh[row][fp] = {feat 2fp, feat 2fp+1}, row' in [0,2N).
// ---------------------------------------------------------------------------
__global__ __launch_bounds__(256) void ln_xw_kernel(
    const float* __restrict__ h,
    const float* __restrict__ gamma,
    const float* __restrict__ beta,
    const float* __restrict__ Wp,
    const float* __restrict__ Wn,
    const float* __restrict__ inv,
    __hip_bfloat162* __restrict__ xh)
{
    __shared__ float sWp[H * H];
    __shared__ float sWn[H * H];
    __shared__ float sHn[8][H];

    int tid = threadIdx.x;
    for (int i = tid; i < H * H; i += 256) { sWp[i] = Wp[i]; sWn[i] = Wn[i]; }

    int lane = tid & 31;
    int r    = tid >> 5;
    int row  = blockIdx.x * 8 + r;

    float x = h[row * H + lane];
    float s = x;
    #pragma unroll
    for (int m = 16; m >= 1; m >>= 1) s += __shfl_xor(s, m);
    float mu = s * (1.0f / 32.0f);
    float d  = x - mu;
    float v  = d * d;
    #pragma unroll
    for (int m = 16; m >= 1; m >>= 1) v += __shfl_xor(v, m);
    float rstd = rsqrtf(v * (1.0f / 32.0f) + LN_EPS);
    float hn   = d * rstd * gamma[lane] + beta[lane];

    sHn[r][lane] = hn;
    __syncthreads();

    float accp = 0.f, accn = 0.f;
    #pragma unroll
    for (int k = 0; k < H; k++) {
        float hk = sHn[r][k];
        accp += hk * sWp[k * H + lane];
        accn += hk * sWn[k * H + lane];
    }
    float vp = accp * inv[row];
    float vn = accn * inv[N_NODES + row];

    // pack feature pairs: even lane stores {self, odd-partner}
    float vp_nb = __shfl_xor(vp, 1);
    float vn_nb = __shfl_xor(vn, 1);
    if ((lane & 1) == 0) {
        __hip_bfloat162 pv, nv;
        pv.x = __float2bfloat16(vp); pv.y = __float2bfloat16(vp_nb);
        nv.x = __float2bfloat16(vn); nv.y = __float2bfloat16(vn_nb);
        int fp = lane >> 1;
        xh[row * 16 + fp]               = pv;
        xh[(N_NODES + row) * 16 + fp]   = nv;
    }
}

// ---------------------------------------------------------------------------
// Kernel 4: atomic-free gather, wave per row, POS+NEG INTERLEAVED for 2x MLP
// (8 cache lines in flight per wave). Then bias + psi GEMV + tanh + damping.
// ---------------------------------------------------------------------------
__global__ __launch_bounds__(256) void gather_final_kernel(
    const float* __restrict__ h,
    const float* __restrict__ gamma,
    const float* __restrict__ beta,
    const __hip_bfloat162* __restrict__ xh,
    const int* __restrict__ slot,
    const float* __restrict__ inv,
    const int2* __restrict__ rs2,
    const float* __restrict__ bp,
    const float* __restrict__ bn,
    const float* __restrict__ Wpsi,
    float* __restrict__ out)
{
    __shared__ float sW[2 * H * H];
    __shared__ float sP[4][H];
    __shared__ float sM[4][H];

    int tid = threadIdx.x;
    for (int i = tid; i < 2 * H * H; i += 256) sW[i] = Wpsi[i];

    int wave = tid >> 6;
    int lane = tid & 63;
    int grp  = lane >> 4;        // edge group 0..3
    int fp   = lane & 15;        // feature pair 0..15
    int row  = blockIdx.x * 4 + wave;
    int rn   = N_NODES + row;

    int2 RP = rs2[row];
    int2 RN = rs2[rn];

    float ap0 = 0.f, ap1 = 0.f, an0 = 0.f, an1 = 0.f;
    int np = (RP.y - RP.x) >> 4;
    int nn = (RN.y - RN.x) >> 4;
    int nmax = np > nn ? np : nn;
    int slp = 0, sln = 0;

    for (int c = 0; c < nmax; c++) {
        bool dop = c < np, don = c < nn;
        if ((c & 3) == 0) {
            if (dop) { int jl = RP.x + (c << 4) + lane; slp = slot[jl < RP.y ? jl : RP.y - 1]; }
            if (don) { int jl = RN.x + (c << 4) + lane; sln = slot[jl < RN.y ? jl : RN.y - 1]; }
        }
        int sb = ((c & 3) << 4) + (grp << 2);
        __hip_bfloat162 vp0, vp1, vp2, vp3, vn0, vn1, vn2, vn3;
        if (dop) {
            int s0 = __shfl(slp, sb + 0, 64), s1 = __shfl(slp, sb + 1, 64);
            int s2 = __shfl(slp, sb + 2, 64), s3 = __shfl(slp, sb + 3, 64);
            vp0 = xh[s0 * 16 + fp]; vp1 = xh[s1 * 16 + fp];
            vp2 = xh[s2 * 16 + fp]; vp3 = xh[s3 * 16 + fp];
        }
        if (don) {
            int s0 = __shfl(sln, sb + 0, 64), s1 = __shfl(sln, sb + 1, 64);
            int s2 = __shfl(sln, sb + 2, 64), s3 = __shfl(sln, sb + 3, 64);
            vn0 = xh[s0 * 16 + fp]; vn1 = xh[s1 * 16 + fp];
            vn2 = xh[s2 * 16 + fp]; vn3 = xh[s3 * 16 + fp];
        }
        if (dop) {
            ap0 += __bfloat162float(vp0.x) + __bfloat162float(vp1.x)
                 + __bfloat162float(vp2.x) + __bfloat162float(vp3.x);
            ap1 += __bfloat162float(vp0.y) + __bfloat162float(vp1.y)
                 + __bfloat162float(vp2.y) + __bfloat162float(vp3.y);
        }
        if (don) {
            an0 += __bfloat162float(vn0.x) + __bfloat162float(vn1.x)
                 + __bfloat162float(vn2.x) + __bfloat162float(vn3.x);
            an1 += __bfloat162float(vn0.y) + __bfloat162float(vn1.y)
                 + __bfloat162float(vn2.y) + __bfloat162float(vn3.y);
        }
    }

    // tails (<16 edges each), group-strided
    {
        int jt = RP.x + (np << 4);
        if (jt < RP.y) {
            int cnt = RP.y - jt;
            int ms = (lane < cnt) ? slot[jt + lane] : 0;
            for (int jj = grp; jj < cnt; jj += 4) {
                int s = __shfl(ms, jj, 64);
                __hip_bfloat162 v = xh[s * 16 + fp];
                ap0 += __bfloat162float(v.x);
                ap1 += __bfloat162float(v.y);
            }
        }
    }
    {
        int jt = RN.x + (nn << 4);
        if (jt < RN.y) {
            int cnt = RN.y - jt;
            int ms = (lane < cnt) ? slot[jt + lane] : 0;
            for (int jj = grp; jj < cnt; jj += 4) {
                int s = __shfl(ms, jj, 64);
                __hip_bfloat162 v = xh[s * 16 + fp];
                an0 += __bfloat162float(v.x);
                an1 += __bfloat162float(v.y);
            }
        }
    }

    // reduce across the 4 edge groups
    ap0 += __shfl_xor(ap0, 16); ap0 += __shfl_xor(ap0, 32);
    ap1 += __shfl_xor(ap1, 16); ap1 += __shfl_xor(ap1, 32);
    an0 += __shfl_xor(an0, 16); an0 += __shfl_xor(an0, 32);
    an1 += __shfl_xor(an1, 16); an1 += __shfl_xor(an1, 32);

    // self loops (already inv-scaled) + outer inv + bias
    __hip_bfloat162 svp = xh[row * 16 + fp];
    __hip_bfloat162 svn = xh[rn * 16 + fp];
    float ivp = inv[row], ivn = inv[rn];
    float hp0 = ivp * (ap0 + __bfloat162float(svp.x)) + bp[2 * fp];
    float hp1 = ivp * (ap1 + __bfloat162float(svp.y)) + bp[2 * fp + 1];
    float hm0 = ivn * (an0 + __bfloat162float(svn.x)) + bn[2 * fp];
    float hm1 = ivn * (an1 + __bfloat162float(svn.y)) + bn[2 * fp + 1];

    if (grp == 0) {
        sP[wave][2 * fp]     = hp0;
        sP[wave][2 * fp + 1] = hp1;
        sM[wave][2 * fp]     = hm0;
        sM[wave][2 * fp + 1] = hm1;
    }
    __syncthreads();

    // ---- epilogue: LN recompute + psi + tanh + damping + clip (128 thr) ----
    if (tid < 128) {
        int r     = tid >> 5;
        int lane2 = tid & 31;
        int row2  = blockIdx.x * 4 + r;

        float x = h[row2 * H + lane2];
        float s = x;
        #pragma unroll
        for (int m = 16; m >= 1; m >>= 1) s += __shfl_xor(s, m);
        float mu = s * (1.0f / 32.0f);
        float d  = x - mu;
        float v  = d * d;
        #pragma unroll
        for (int m = 16; m >= 1; m >>= 1) v += __shfl_xor(v, m);
        float rstd = rsqrtf(v * (1.0f / 32.0f) + LN_EPS);
        float hn   = d * rstd * gamma[lane2] + beta[lane2];

        float acc = 0.f;
        #pragma unroll
        for (int k = 0; k < H; k++) {
            acc += sP[r][k] * sW[k * H + lane2];
            acc += sM[r][k] * sW[(H + k) * H + lane2];
        }

        float delta = tanhf(acc) - DAMPING * hn;
        delta = fminf(fmaxf(delta, -50.f), 50.f);
        out[row2 * H + lane2] = delta;
    }
}

// ---------------------------------------------------------------------------
extern "C" void kernel_launch(void* const* d_in, const int* in_sizes, int n_in,
                              void* d_out, int out_size, void* d_ws, size_t ws_size,
                              hipStream_t stream)
{
    const float* h      = (const float*)d_in[1];
    const int*   ep     = (const int*)  d_in[2];   // (2, E)
    const int*   en     = (const int*)  d_in[3];
    const float* gamma  = (const float*)d_in[4];
    const float* beta   = (const float*)d_in[5];
    const float* Wp     = (const float*)d_in[6];
    const float* bp     = (const float*)d_in[7];
    const float* Wn     = (const float*)d_in[8];
    const float* bn     = (const float*)d_in[9];
    const float* Wpsi   = (const float*)d_in[10];
    float* out = (float*)d_out;

    // workspace layout (43.3 MB total, no aliasing):
    unsigned int* buf = (unsigned int*)d_ws;                    // NBUCK*CAP u32 (28.0 MB)
    __hip_bfloat162* xh = (__hip_bfloat162*)(buf + NBUCK * CAP); // 2N*16 (12.8 MB)
    int2*  rs2  = (int2*)(xh + (size_t)TWO_N * 16);             // 2N int2 (1.6 MB)
    float* inv  = (float*)(rs2 + TWO_N);                        // 2N f32 (0.8 MB)
    int*   gcur = (int*)(inv + TWO_N);                          // NBUCK

    init_gcur_kernel<<<4, 256, 0, stream>>>(gcur);

    bucket_scatter_kernel<<<NBLK_A, 256, 0, stream>>>(ep, en, gcur, buf);

    csr_build_kernel<<<NBUCK, 256, 0, stream>>>(gcur, buf, rs2, inv);

    ln_xw_kernel<<<N_NODES / 8, 256, 0, stream>>>(h, gamma, beta, Wp, Wn, inv, xh);

    gather_final_kernel<<<N_NODES / 4, 256, 0, stream>>>(
        h, gamma, beta, xh, (const int*)buf, inv, rs2, bp, bn, Wpsi, out);
}